// Round 1
// baseline (137.724 us; speedup 1.0000x reference)
//
#include <hip/hip_runtime.h>
#include <hip/hip_bf16.h>

#define BATCH 4096
#define NROWS 8192
#define DIM 256
#define CS_COUNT 8              // column splits
#define COLS_PER_CS (NROWS / CS_COUNT)   // 1024
#define ROWS_PER_BLOCK 128
#define ROWS_PER_WAVE 32

typedef __attribute__((ext_vector_type(4))) float f32x4;
typedef __attribute__((ext_vector_type(8))) short short8;

static __device__ __forceinline__ unsigned short f2bf(float x) {
    __hip_bfloat16 h = __float2bfloat16(x);
    return *reinterpret_cast<unsigned short*>(&h);
}
static __device__ __forceinline__ float bf2f(unsigned short u) {
    union { unsigned int i; float f; } x;
    x.i = ((unsigned int)u) << 16;
    return x.f;
}

// ---------------------------------------------------------------------------
// Kernel A: concat + L2-normalize rows, cast to bf16, store into ws.
// One wave per row: 64 lanes x float4 = 256 elements.
// ---------------------------------------------------------------------------
__global__ void normalize_kernel(const float* __restrict__ z_i,
                                 const float* __restrict__ z_j,
                                 unsigned short* __restrict__ zn) {
    int wid  = (blockIdx.x * blockDim.x + threadIdx.x) >> 6;   // row
    int lane = threadIdx.x & 63;
    if (wid >= NROWS) return;
    const float* src = (wid < BATCH) ? (z_i + (size_t)wid * DIM)
                                     : (z_j + (size_t)(wid - BATCH) * DIM);
    float4 v = reinterpret_cast<const float4*>(src)[lane];
    float ss = v.x * v.x + v.y * v.y + v.z * v.z + v.w * v.w;
#pragma unroll
    for (int m = 1; m < 64; m <<= 1) ss += __shfl_xor(ss, m);
    float inv = 1.0f / fmaxf(sqrtf(ss), 1e-8f);
    ushort4 o;
    o.x = f2bf(v.x * inv);
    o.y = f2bf(v.y * inv);
    o.z = f2bf(v.z * inv);
    o.w = f2bf(v.w * inv);
    reinterpret_cast<ushort4*>(zn + (size_t)wid * DIM)[lane] = o;
}

// ---------------------------------------------------------------------------
// Kernel B: fused sim-GEMM + sum-of-exp per row.
// Grid: 512 blocks = 64 row-blocks x 8 col-splits. Block = 4 waves.
// Wave owns 32 rows (2 MFMA row-tiles), iterates its 1024-col split in
// 16-col tiles. A-fragments register-resident for the whole kernel.
// ---------------------------------------------------------------------------
__device__ __forceinline__ void load_bfrags(const unsigned short* __restrict__ zn,
                                            int c, int lr, int lk, short8* b) {
#pragma unroll
    for (int kk = 0; kk < 8; ++kk)
        b[kk] = *reinterpret_cast<const short8*>(
            zn + (size_t)(c + lr) * DIM + kk * 32 + lk * 8);
}

__device__ __forceinline__ void compute_tile(const short8 (&af)[2][8],
                                             const short8* bf,
                                             int c, int row0, int lr, int lk,
                                             float (&dacc)[2][4]) {
    f32x4 acc0 = {0.f, 0.f, 0.f, 0.f};
    f32x4 acc1 = {0.f, 0.f, 0.f, 0.f};
#pragma unroll
    for (int kk = 0; kk < 8; ++kk) {
        acc0 = __builtin_amdgcn_mfma_f32_16x16x32_bf16(af[0][kk], bf[kk], acc0, 0, 0, 0);
        acc1 = __builtin_amdgcn_mfma_f32_16x16x32_bf16(af[1][kk], bf[kk], acc1, 0, 0, 0);
    }
    int col = c + lr;              // C/D: col = lane&15, row = (lane>>4)*4 + j
    // row-tile 0
    if (c == row0) {               // uniform branch: diagonal crosses this tile
#pragma unroll
        for (int j = 0; j < 4; ++j) {
            float e = __expf(acc0[j] * 2.0f);
            if (col == row0 + lk * 4 + j) e = 0.0f;   // exclude diagonal
            dacc[0][j] += e;
        }
    } else {
#pragma unroll
        for (int j = 0; j < 4; ++j) dacc[0][j] += __expf(acc0[j] * 2.0f);
    }
    // row-tile 1
    if (c == row0 + 16) {
#pragma unroll
        for (int j = 0; j < 4; ++j) {
            float e = __expf(acc1[j] * 2.0f);
            if (col == row0 + 16 + lk * 4 + j) e = 0.0f;
            dacc[1][j] += e;
        }
    } else {
#pragma unroll
        for (int j = 0; j < 4; ++j) dacc[1][j] += __expf(acc1[j] * 2.0f);
    }
}

__global__ __launch_bounds__(256, 2)
void simloss_kernel(const unsigned short* __restrict__ zn,
                    float* __restrict__ part /* [CS_COUNT][NROWS] */) {
    int wave = threadIdx.x >> 6;
    int lane = threadIdx.x & 63;
    int lr = lane & 15;            // fragment row / col index
    int lk = lane >> 4;            // k-subgroup
    int rb = blockIdx.x & 63;
    int cs = blockIdx.x >> 6;
    int row0 = rb * ROWS_PER_BLOCK + wave * ROWS_PER_WAVE;
    int c0 = cs * COLS_PER_CS;

    // A fragments: 2 row-tiles x 8 k-frags, resident in 64 VGPRs
    short8 af[2][8];
#pragma unroll
    for (int t = 0; t < 2; ++t)
#pragma unroll
        for (int kk = 0; kk < 8; ++kk)
            af[t][kk] = *reinterpret_cast<const short8*>(
                zn + (size_t)(row0 + t * 16 + lr) * DIM + kk * 32 + lk * 8);

    float dacc[2][4] = {{0.f, 0.f, 0.f, 0.f}, {0.f, 0.f, 0.f, 0.f}};

    short8 bufA[8], bufB[8];
    load_bfrags(zn, c0, lr, lk, bufA);
#pragma unroll 1
    for (int ct = 0; ct < COLS_PER_CS / 16; ct += 2) {
        int cA = c0 + ct * 16;
        int cB = cA + 16;
        load_bfrags(zn, cB, lr, lk, bufB);                 // prefetch odd
        compute_tile(af, bufA, cA, row0, lr, lk, dacc);
        if (ct + 2 < COLS_PER_CS / 16)
            load_bfrags(zn, cA + 32, lr, lk, bufA);        // prefetch next even
        compute_tile(af, bufB, cB, row0, lr, lk, dacc);
    }

    // reduce dacc across the 16 lanes sharing the same rows (lr dimension)
#pragma unroll
    for (int t = 0; t < 2; ++t)
#pragma unroll
        for (int j = 0; j < 4; ++j) {
            float v = dacc[t][j];
            v += __shfl_xor(v, 1);
            v += __shfl_xor(v, 2);
            v += __shfl_xor(v, 4);
            v += __shfl_xor(v, 8);
            if (lr == 0)
                part[(size_t)cs * NROWS + row0 + t * 16 + lk * 4 + j] = v;
        }
}

// ---------------------------------------------------------------------------
// Kernel C: per-row loss contribution: log(sum of partials) - 2*dot(zn_r, zn_{r^4096})
// Block = 4 waves, wave handles 8 rows sequentially. Grid = 256 -> 8192 rows.
// ---------------------------------------------------------------------------
__global__ void rowloss_kernel(const unsigned short* __restrict__ zn,
                               const float* __restrict__ part,
                               float* __restrict__ cpart) {
    int wave = threadIdx.x >> 6;
    int lane = threadIdx.x & 63;
    float wsum = 0.0f;
#pragma unroll 1
    for (int it = 0; it < 8; ++it) {
        int r = blockIdx.x * 32 + wave * 8 + it;
        ushort4 za = reinterpret_cast<const ushort4*>(zn + (size_t)r * DIM)[lane];
        ushort4 zb = reinterpret_cast<const ushort4*>(zn + (size_t)(r ^ BATCH) * DIM)[lane];
        float dot = bf2f(za.x) * bf2f(zb.x) + bf2f(za.y) * bf2f(zb.y) +
                    bf2f(za.z) * bf2f(zb.z) + bf2f(za.w) * bf2f(zb.w);
#pragma unroll
        for (int m = 1; m < 64; m <<= 1) dot += __shfl_xor(dot, m);
        float den = (lane < CS_COUNT) ? part[(size_t)lane * NROWS + r] : 0.0f;
        den += __shfl_xor(den, 4);
        den += __shfl_xor(den, 2);
        den += __shfl_xor(den, 1);
        if (lane == 0) wsum += logf(den) - 2.0f * dot;
    }
    __shared__ float red[4];
    if (lane == 0) red[wave] = wsum;
    __syncthreads();
    if (threadIdx.x == 0)
        cpart[blockIdx.x] = red[0] + red[1] + red[2] + red[3];
}

// ---------------------------------------------------------------------------
// Kernel D: final reduction of 256 block partials -> scalar loss / n
// ---------------------------------------------------------------------------
__global__ void final_kernel(const float* __restrict__ cpart,
                             float* __restrict__ out) {
    int lane = threadIdx.x & 63;
    int wave = threadIdx.x >> 6;
    double v = (double)cpart[threadIdx.x];
#pragma unroll
    for (int m = 1; m < 64; m <<= 1) v += __shfl_xor(v, m);
    __shared__ double red[4];
    if (lane == 0) red[wave] = v;
    __syncthreads();
    if (threadIdx.x == 0)
        out[0] = (float)((red[0] + red[1] + red[2] + red[3]) / (double)NROWS);
}

// ---------------------------------------------------------------------------
extern "C" void kernel_launch(void* const* d_in, const int* in_sizes, int n_in,
                              void* d_out, int out_size, void* d_ws, size_t ws_size,
                              hipStream_t stream) {
    const float* z_i = (const float*)d_in[0];
    const float* z_j = (const float*)d_in[1];
    float* out = (float*)d_out;
    char* ws = (char*)d_ws;

    unsigned short* zn = (unsigned short*)ws;                        // 4 MB
    float* part  = (float*)(ws + (size_t)NROWS * DIM * 2);           // 256 KB
    float* cpart = (float*)(ws + (size_t)NROWS * DIM * 2 + (size_t)CS_COUNT * NROWS * 4);

    normalize_kernel<<<NROWS / 4, 256, 0, stream>>>(z_i, z_j, zn);
    simloss_kernel<<<(NROWS / ROWS_PER_BLOCK) * CS_COUNT, 256, 0, stream>>>(zn, part);
    rowloss_kernel<<<NROWS / 32, 256, 0, stream>>>(zn, part, cpart);
    final_kernel<<<1, 256, 0, stream>>>(cpart, out);
}